// Round 5
// baseline (1070.493 us; speedup 1.0000x reference)
//
#include <hip/hip_runtime.h>

typedef __attribute__((ext_vector_type(8))) short bf16x8;
typedef __attribute__((ext_vector_type(4))) float f32x4;
typedef __attribute__((ext_vector_type(2))) unsigned int u32x2;

#define MFMA16(a,b,c) __builtin_amdgcn_mfma_f32_16x16x32_bf16(a,b,c,0,0,0)
#define A_GELU 0.7978845608028654f

// ---- LDS byte offsets (all 16B aligned) ----
#define OFF_W1B   0u        // ushort[256][72]  W1 mirror [hf4][f]
#define OFF_W2F   36864u    // ushort[64][264]  W2 mirror [f][hf4], XOR-swizzled cols
#define OFF_XK    70656u    // ushort[16][72]   xk row-major
#define OFF_XQ    72960u    // ushort[16][72]
#define OFF_X2    75264u    // ushort[16][264]  X2 row-major
#define OFF_X2B   83712u    // ushort[16][264]  X2_bar row-major
#define OFF_DZ2B  92160u    // ushort[16][72]   dZ2 row-major
#define OFF_DZ1CT 94464u    // ushort[256][40]  dZ1 col-major, k 16..31 zero
#define OFF_DZ2CT 114944u   // ushort[64][40]   dZ2 col-major, k 16..31 zero
#define OFF_XKCT  120064u   // ushort[64][40]   xk col-major [f][CS], k-pad zero
#define OFF_X2CT  125184u   // ushort[256][40]  X2 col-major [hf4][CS], k-pad zero
#define OFF_M1    145664u   // ushort[16][40]
#define OFF_M2    146944u   // ushort[16][40]
#define OFF_Z2F   148224u   // float[16][68]  Z2 partial (kh==1)
#define OFF_Z2G   152576u   // float[16][68]  Z2 partial (kh==0)
#define OFF_TGT   156928u   // float[16][64]
#define OFF_B2    161024u   // float[2][64]
#define OFF_COEF  161536u   // float[16]
#define OFF_CL    161600u   // float[1]
#define SMEM_BYTES 161616u

// swizzled ushort-col within a sW2fu row (16B-block XOR)
#define W2COL(col, row) ((col) ^ (((row)&7)<<3))

__device__ __forceinline__ float fast_tanh(float u){
    float e = __expf(2.0f*u);
    return 1.0f - 2.0f/(e + 1.0f);
}
__device__ __forceinline__ float gelu_f(float x){
    float t = fast_tanh(A_GELU*(x + 0.044715f*x*x*x));
    return 0.5f*x*(1.0f+t);
}
__device__ __forceinline__ float dgelu_f(float x){
    float x2 = x*x;
    float t = fast_tanh(A_GELU*x*(1.0f + 0.044715f*x2));
    return 0.5f*x*((1.0f-t*t)*(A_GELU + 0.1070322243f*x2)) + 0.5f*(1.0f+t);
}
__device__ __forceinline__ short f2bf(float f){
    unsigned u = __builtin_bit_cast(unsigned, f);
    u += 0x7FFFu + ((u >> 16) & 1u);
    return (short)(u >> 16);
}
__device__ __forceinline__ float bf2f(unsigned short s){
    unsigned u = ((unsigned)s) << 16;
    return __builtin_bit_cast(float, u);
}
// packed f32 pair -> bf16 pair (lo = a, hi = b), RNE
__device__ __forceinline__ unsigned pkbf(float a, float b){
    unsigned r;
    asm("v_cvt_pk_bf16_f32 %0, %1, %2" : "=v"(r) : "v"(a), "v"(b));
    return r;
}
__device__ __forceinline__ bf16x8 ldfrag(const unsigned short* p){
    return *(const bf16x8*)p;
}

__global__ __launch_bounds__(512, 1)
void ttt_m2(const float* __restrict__ XQ, const float* __restrict__ XK,
            const float* __restrict__ XV, const float* __restrict__ coeff,
            const float* __restrict__ coeff_last,
            const float* __restrict__ W1g, const float* __restrict__ b1g,
            const float* __restrict__ W2g, const float* __restrict__ b2g,
            const float* __restrict__ gammag, const float* __restrict__ betag,
            float* __restrict__ out)
{
    const int h  = blockIdx.x;      // head 0..63
    const int t  = threadIdx.x;     // 0..511
    const int l  = t & 63;          // lane
    const int w  = t >> 6;          // wave 0..7
    const int lo = l & 15;
    const int hi = l >> 4;          // 0..3

    extern __shared__ char smem[];
    unsigned short* sW1bu  = (unsigned short*)(smem + OFF_W1B);
    unsigned short* sW2fu  = (unsigned short*)(smem + OFF_W2F);
    unsigned short* sxku   = (unsigned short*)(smem + OFF_XK);
    unsigned short* sxqu   = (unsigned short*)(smem + OFF_XQ);
    unsigned short* sX2u   = (unsigned short*)(smem + OFF_X2);
    unsigned short* sX2bu  = (unsigned short*)(smem + OFF_X2B);
    unsigned short* sdZ2bu = (unsigned short*)(smem + OFF_DZ2B);
    unsigned short* sdZ1ct = (unsigned short*)(smem + OFF_DZ1CT);
    unsigned short* sdZ2ct = (unsigned short*)(smem + OFF_DZ2CT);
    unsigned short* sxkct  = (unsigned short*)(smem + OFF_XKCT);
    unsigned short* sX2ct  = (unsigned short*)(smem + OFF_X2CT);
    unsigned short* sM1u   = (unsigned short*)(smem + OFF_M1);
    unsigned short* sM2u   = (unsigned short*)(smem + OFF_M2);
    float* sZ2f  = (float*)(smem + OFF_Z2F);
    float* sZ2g  = (float*)(smem + OFF_Z2G);
    float* stgt  = (float*)(smem + OFF_TGT);
    float* b2f   = (float*)(smem + OFF_B2);
    float* scoef = (float*)(smem + OFF_COEF);
    float* sCL   = (float*)(smem + OFF_CL);

    const int base1 = h*16384;   // W1 [64][256]
    const int base2 = h*16384;   // W2 [256][64]

    // ---------------- init ----------------
    float mW1[4][2][4];   // D=[f][hf4]: m = mt*16+hi*4+reg, n = (2w+tix)*16+lo
    float mW2[2][4][4];   // D=[hf4][f]: m = (2w+mi)*16+hi*4+reg, n = nt*16+lo
    #pragma unroll
    for (int mt = 0; mt < 4; ++mt)
      #pragma unroll
      for (int tix = 0; tix < 2; ++tix)
        #pragma unroll
        for (int reg = 0; reg < 4; ++reg) {
            const int m = mt*16 + hi*4 + reg, n = (2*w + tix)*16 + lo;
            mW1[mt][tix][reg] = W1g[base1 + m*256 + n];
        }
    #pragma unroll
    for (int mi = 0; mi < 2; ++mi)
      #pragma unroll
      for (int nt = 0; nt < 4; ++nt)
        #pragma unroll
        for (int reg = 0; reg < 4; ++reg) {
            const int m = (2*w + mi)*16 + hi*4 + reg, n = nt*16 + lo;
            mW2[mi][nt][reg] = W2g[base2 + m*64 + n];
        }
    float b1reg[2];
    b1reg[0] = b1g[h*256 + (2*w)*16 + lo];
    b1reg[1] = b1g[h*256 + (2*w+1)*16 + lo];

    // bf16 mirrors (cooperative)
    for (int i = 0; i < 32; ++i) {
        const int idx = i*512 + t;
        const int m = idx >> 8, n = idx & 255;
        sW1bu[n*72 + m] = f2bf(W1g[base1 + idx]);
    }
    for (int i = 0; i < 32; ++i) {
        const int idx = i*512 + t;
        const int hf = idx >> 6, f = idx & 63;
        sW2fu[f*264 + W2COL(hf, f)] = f2bf(W2g[base2 + idx]);
    }
    if (t < 64) b2f[t] = b2g[h*64 + t];
    // zero k-pads (only k<16 ever rewritten)
    if (t < 256) {
        for (int k = 16; k < 40; ++k) { sdZ1ct[t*40 + k] = 0; sX2ct[t*40 + k] = 0; }
    }
    if (t < 64) {
        for (int k = 16; k < 40; ++k) { sdZ2ct[t*40 + k] = 0; sxkct[t*40 + k] = 0; }
    }
    if (t < 16) {
        for (int k = 16; k < 40; ++k) { sM1u[t*40 + k] = 0; sM2u[t*40 + k] = 0; }
    }

    const float gj = gammag[(h & 15)*64 + l];
    const float bj = betag [(h & 15)*64 + l];
    __syncthreads();

    for (int ci = 0; ci < 128; ++ci) {
        const int cb = ci*65536 + h*1024;

        // ---- P0: stage xk/xq/tgt + xk col-major; coeffs ----
        {
            const int r0 = w*2;
            const float xk0 = XK[cb + r0*64 + l],     xq0 = XQ[cb + r0*64 + l];
            const float xk1 = XK[cb + (r0+1)*64 + l], xq1 = XQ[cb + (r0+1)*64 + l];
            const float xv0 = XV[cb + r0*64 + l],     xv1 = XV[cb + (r0+1)*64 + l];
            const unsigned pkk = pkbf(xk0, xk1);
            const unsigned pkq = pkbf(xq0, xq1);
            sxku[r0*72 + l]     = (unsigned short)pkk;
            sxku[(r0+1)*72 + l] = (unsigned short)(pkk >> 16);
            sxqu[r0*72 + l]     = (unsigned short)pkq;
            sxqu[(r0+1)*72 + l] = (unsigned short)(pkq >> 16);
            *(unsigned*)&sxkct[l*40 + r0] = pkk;
            stgt[r0*64 + l]     = xv0 - xk0;
            stgt[(r0+1)*64 + l] = xv1 - xk1;
        }
        if (t < 16)  scoef[t] = coeff[ci*1024 + h*16 + t];
        if (t == 16) sCL[0]   = coeff_last[ci*64 + h];
        __syncthreads();                                        // B1
        const float clv = sCL[0];
        const float c15 = scoef[15];

        // ---- PA: Z1 = xk@W1 + b1 ; X2 (row-major + col-major) ; wave0: M1' ----
        float z1s[8];
        bf16x8 afk0 = ldfrag(sxku + lo*72 + hi*8);
        bf16x8 afk1 = ldfrag(sxku + lo*72 + 32 + hi*8);
        #pragma unroll
        for (int tix = 0; tix < 2; ++tix) {
            const int n = (2*w + tix)*16 + lo;
            f32x4 acc = {b1reg[tix], b1reg[tix], b1reg[tix], b1reg[tix]};
            acc = MFMA16(afk0, ldfrag(sW1bu + n*72 + hi*8), acc);
            acc = MFMA16(afk1, ldfrag(sW1bu + n*72 + 32 + hi*8), acc);
            float g[4];
            #pragma unroll
            for (int reg = 0; reg < 4; ++reg) {
                z1s[tix*4 + reg] = acc[reg];
                g[reg] = gelu_f(acc[reg]);
            }
            const unsigned p01 = pkbf(g[0], g[1]), p23 = pkbf(g[2], g[3]);
            sX2u[(hi*4+0)*264 + n] = (unsigned short)p01;
            sX2u[(hi*4+1)*264 + n] = (unsigned short)(p01 >> 16);
            sX2u[(hi*4+2)*264 + n] = (unsigned short)p23;
            sX2u[(hi*4+3)*264 + n] = (unsigned short)(p23 >> 16);
            *(u32x2*)&sX2ct[n*40 + hi*4] = (u32x2){p01, p23};
        }
        if (w == 0) {   // A1 = xq@xk^T ; M1'
            bf16x8 aq0 = ldfrag(sxqu + lo*72 + hi*8);
            bf16x8 aq1 = ldfrag(sxqu + lo*72 + 32 + hi*8);
            f32x4 a1 = {0.f, 0.f, 0.f, 0.f};
            a1 = MFMA16(aq0, afk0, a1);
            a1 = MFMA16(aq1, afk1, a1);
            #pragma unroll
            for (int reg = 0; reg < 4; ++reg) {
                const int r = hi*4 + reg;
                const float cr = scoef[r];
                const float v = (lo <= r) ? (-cr*(a1[reg] + 1.0f)) : 0.0f;
                sM1u[r*40 + lo] = f2bf(v);
            }
        }
        __syncthreads();                                        // B2

        // ---- PB: Z2 = X2@W2 + b2 (K split, two partial buffers) ----
        const int tile = w & 3, kh = w >> 2;
        const int nf = tile*16 + lo;                            // f-col 0..63
        {
            f32x4 accPB;
            if (kh == 0) {
                const float b2v = b2f[(ci & 1)*64 + nf];
                accPB = (f32x4){b2v, b2v, b2v, b2v};
            } else accPB = (f32x4){0.f, 0.f, 0.f, 0.f};
            #pragma unroll
            for (int s = 0; s < 4; ++s) {
                const int k = (kh*4 + s)*32 + hi*8;
                accPB = MFMA16(ldfrag(sX2u + lo*264 + k),
                               ldfrag(sW2fu + nf*264 + W2COL(k, nf)), accPB);
            }
            float* dst = (kh == 0) ? sZ2g : sZ2f;
            #pragma unroll
            for (int reg = 0; reg < 4; ++reg)
                dst[(hi*4 + reg)*68 + nf] = accPB[reg];
        }
        __syncthreads();                                        // B3

        // ---- PC: LN-fused-L2 backward -> dZ2 (row-major + col-major) ----
        {
            float dzp[2];
            #pragma unroll
            for (int i = 0; i < 2; ++i) {
                const int r = w*2 + i;
                const float z2 = sZ2f[r*68 + l] + sZ2g[r*68 + l];
                float s1 = z2, s2 = z2*z2;
                #pragma unroll
                for (int m = 1; m < 64; m <<= 1) { s1 += __shfl_xor(s1, m); s2 += __shfl_xor(s2, m); }
                const float mu   = s1*(1.0f/64.0f);
                const float var  = s2*(1.0f/64.0f) - mu*mu;
                const float rstd = rsqrtf(var + 1e-6f);
                const float xh   = (z2 - mu)*rstd;
                const float go   = gj*xh + bj - stgt[r*64 + l];
                const float gg   = go*gj;
                float u1 = gg, u2 = gg*xh;
                #pragma unroll
                for (int m = 1; m < 64; m <<= 1) { u1 += __shfl_xor(u1, m); u2 += __shfl_xor(u2, m); }
                dzp[i] = (64.0f*gg - u1 - xh*u2)*(rstd*(1.0f/64.0f));
            }
            const unsigned pk = pkbf(dzp[0], dzp[1]);
            sdZ2bu[(w*2)*72 + l]   = (unsigned short)pk;
            sdZ2bu[(w*2+1)*72 + l] = (unsigned short)(pk >> 16);
            *(unsigned*)&sdZ2ct[l*40 + w*2] = pk;
        }
        __syncthreads();                                        // B4

        // ---- PD: dZ1 = (dZ2@W2^T) * dgelu(Z1) -> sdZ1ct ; b1 carry ----
        float b1old[2];
        {
            bf16x8 ad0 = ldfrag(sdZ2bu + lo*72 + hi*8);
            bf16x8 ad1 = ldfrag(sdZ2bu + lo*72 + 32 + hi*8);
            #pragma unroll
            for (int tix = 0; tix < 2; ++tix) {
                const int n = (2*w + tix)*16 + lo;              // hf col
                f32x4 acc = {0.f, 0.f, 0.f, 0.f};
                bf16x8 bw;
                #pragma unroll
                for (int j = 0; j < 8; ++j)
                    bw[j] = (short)sW2fu[(hi*8 + j)*264 + (n ^ (j<<3))];
                acc = MFMA16(ad0, bw, acc);
                #pragma unroll
                for (int j = 0; j < 8; ++j)
                    bw[j] = (short)sW2fu[(32 + hi*8 + j)*264 + (n ^ (j<<3))];
                acc = MFMA16(ad1, bw, acc);
                float dv[4];
                float cs = 0.f;
                #pragma unroll
                for (int reg = 0; reg < 4; ++reg) {
                    dv[reg] = acc[reg]*dgelu_f(z1s[tix*4 + reg]);
                    cs += dv[reg];
                }
                *(u32x2*)&sdZ1ct[n*40 + hi*4] =
                    (u32x2){pkbf(dv[0], dv[1]), pkbf(dv[2], dv[3])};
                cs += __shfl_xor(cs, 16);
                cs += __shfl_xor(cs, 32);
                b1old[tix] = b1reg[tix];
                b1reg[tix] -= c15*cs;
            }
        }
        __syncthreads();                                        // B5

        // ---- PE: Z1bar = xq@W1 + b1old + M1'@dZ1 -> X2b ; W1 update ----
        {
            bf16x8 aq0 = ldfrag(sxqu + lo*72 + hi*8);
            bf16x8 aq1 = ldfrag(sxqu + lo*72 + 32 + hi*8);
            bf16x8 am1 = ldfrag(sM1u + lo*40 + hi*8);
            #pragma unroll
            for (int tix = 0; tix < 2; ++tix) {
                const int n = (2*w + tix)*16 + lo;
                f32x4 acc = {b1old[tix], b1old[tix], b1old[tix], b1old[tix]};
                acc = MFMA16(aq0, ldfrag(sW1bu + n*72 + hi*8), acc);
                acc = MFMA16(aq1, ldfrag(sW1bu + n*72 + 32 + hi*8), acc);
                acc = MFMA16(am1, ldfrag(sdZ1ct + n*40 + hi*8), acc);
                float g[4];
                #pragma unroll
                for (int reg = 0; reg < 4; ++reg) g[reg] = gelu_f(acc[reg]);
                const unsigned p01 = pkbf(g[0], g[1]), p23 = pkbf(g[2], g[3]);
                sX2bu[(hi*4+0)*264 + n] = (unsigned short)p01;
                sX2bu[(hi*4+1)*264 + n] = (unsigned short)(p01 >> 16);
                sX2bu[(hi*4+2)*264 + n] = (unsigned short)p23;
                sX2bu[(hi*4+3)*264 + n] = (unsigned short)(p23 >> 16);
            }
            // W1 -= cl * xk^T @ dZ1  (A from sxkct, B from sdZ1ct — all frags)
            bf16x8 bz0 = ldfrag(sdZ1ct + ((2*w)*16 + lo)*40 + hi*8);
            bf16x8 bz1 = ldfrag(sdZ1ct + ((2*w+1)*16 + lo)*40 + hi*8);
            #pragma unroll
            for (int mt = 0; mt < 4; ++mt) {
                bf16x8 axt = ldfrag(sxkct + (mt*16 + lo)*40 + hi*8);
                f32x4 z4 = {0.f,0.f,0.f,0.f};
                f32x4 u0 = MFMA16(axt, bz0, z4);
                f32x4 u1 = MFMA16(axt, bz1, z4);
                #pragma unroll
                for (int reg = 0; reg < 4; ++reg) {
                    mW1[mt][0][reg] -= clv*u0[reg];
                    mW1[mt][1][reg] -= clv*u1[reg];
                }
            }
        }
        __syncthreads();                                        // B6

        // ---- PF-a: W2 update (all frags) ; wave0: A2/M2' ; wave1: b2 carry ----
        {
            bf16x8 bz2[4];
            #pragma unroll
            for (int nt = 0; nt < 4; ++nt)
                bz2[nt] = ldfrag(sdZ2ct + (nt*16 + lo)*40 + hi*8);
            #pragma unroll
            for (int mi = 0; mi < 2; ++mi) {
                bf16x8 ax2 = ldfrag(sX2ct + ((2*w + mi)*16 + lo)*40 + hi*8);
                #pragma unroll
                for (int nt = 0; nt < 4; ++nt) {
                    f32x4 z4 = {0.f,0.f,0.f,0.f};
                    f32x4 u = MFMA16(ax2, bz2[nt], z4);
                    #pragma unroll
                    for (int reg = 0; reg < 4; ++reg)
                        mW2[mi][nt][reg] -= clv*u[reg];
                }
            }
            if (w == 0) {   // A2 = X2b@X2^T ; M2'
                f32x4 a2 = {0.f,0.f,0.f,0.f};
                #pragma unroll
                for (int ks = 0; ks < 8; ++ks) {
                    const int k = ks*32 + hi*8;
                    a2 = MFMA16(ldfrag(sX2bu + lo*264 + k),
                                ldfrag(sX2u + lo*264 + k), a2);
                }
                #pragma unroll
                for (int reg = 0; reg < 4; ++reg) {
                    const int r = hi*4 + reg;
                    const float cr = scoef[r];
                    const float v = (lo <= r) ? (-cr*(a2[reg] + 1.0f)) : 0.0f;
                    sM2u[r*40 + lo] = f2bf(v);
                }
            }
            if (w == 1) {   // b2 carry
                float cs = 0.f;
                #pragma unroll
                for (int k = 0; k < 16; ++k) cs += bf2f(sdZ2ct[l*40 + k]);
                b2f[((ci+1) & 1)*64 + l] = b2f[(ci & 1)*64 + l] - c15*cs;
            }
        }
        __syncthreads();                                        // B7

        // ---- PF-b: Z2bar = X2b@W2 + b2old + M2'@dZ2 (K split) ----
        f32x4 accPF;
        if (kh == 0) {
            const float b2v = b2f[(ci & 1)*64 + nf];
            accPF = (f32x4){b2v, b2v, b2v, b2v};
        } else accPF = (f32x4){0.f, 0.f, 0.f, 0.f};
        #pragma unroll
        for (int s = 0; s < 4; ++s) {
            const int k = (kh*4 + s)*32 + hi*8;
            accPF = MFMA16(ldfrag(sX2bu + lo*264 + k),
                           ldfrag(sW2fu + nf*264 + W2COL(k, nf)), accPF);
        }
        if (kh == 0) {
            accPF = MFMA16(ldfrag(sM2u + lo*40 + hi*8),
                           ldfrag(sdZ2ct + nf*40 + hi*8), accPF);
        } else {
            #pragma unroll
            for (int reg = 0; reg < 4; ++reg)
                sZ2f[(hi*4 + reg)*68 + nf] = accPF[reg];
        }
        __syncthreads();                                        // B8

        // ---- PF-c: final out (kh==0) ; vectorized mirror rewrites ----
        if (kh == 0) {
            #pragma unroll
            for (int reg = 0; reg < 4; ++reg) {
                const int r = hi*4 + reg;
                out[h*131072 + (ci*16 + r)*64 + nf] = accPF[reg] + sZ2f[r*68 + nf];
            }
        }
        #pragma unroll
        for (int mt = 0; mt < 4; ++mt)
          #pragma unroll
          for (int tix = 0; tix < 2; ++tix) {
                const int n = (2*w + tix)*16 + lo, m0 = mt*16 + hi*4;
                *(u32x2*)&sW1bu[n*72 + m0] =
                    (u32x2){pkbf(mW1[mt][tix][0], mW1[mt][tix][1]),
                            pkbf(mW1[mt][tix][2], mW1[mt][tix][3])};
          }
        #pragma unroll
        for (int mi = 0; mi < 2; ++mi)
          #pragma unroll
          for (int nt = 0; nt < 4; ++nt) {
                const int n = nt*16 + lo, m0 = (2*w + mi)*16 + hi*4;
                *(u32x2*)&sW2fu[n*264 + (m0 ^ ((n&7)<<3))] =
                    (u32x2){pkbf(mW2[mi][nt][0], mW2[mi][nt][1]),
                            pkbf(mW2[mi][nt][2], mW2[mi][nt][3])};
          }
        __syncthreads();                                        // B9
    }
}

extern "C" void kernel_launch(void* const* d_in, const int* in_sizes, int n_in,
                              void* d_out, int out_size, void* d_ws, size_t ws_size,
                              hipStream_t stream) {
    const float* XQ  = (const float*)d_in[0];
    const float* XK  = (const float*)d_in[1];
    const float* XV  = (const float*)d_in[2];
    const float* cf  = (const float*)d_in[3];
    const float* cfl = (const float*)d_in[4];
    const float* W1  = (const float*)d_in[5];
    const float* b1  = (const float*)d_in[6];
    const float* W2  = (const float*)d_in[7];
    const float* b2  = (const float*)d_in[8];
    const float* gam = (const float*)d_in[9];
    const float* bet = (const float*)d_in[10];
    float* o = (float*)d_out;

    hipFuncSetAttribute((const void*)ttt_m2,
                        hipFuncAttributeMaxDynamicSharedMemorySize, SMEM_BYTES);
    ttt_m2<<<64, 512, SMEM_BYTES, stream>>>(XQ, XK, XV, cf, cfl, W1, b1, W2, b2, gam, bet, o);
}